// Round 8
// baseline (2773.701 us; speedup 1.0000x reference)
//
#include <hip/hip_runtime.h>
#include <math.h>

#define DEV_INLINE __device__ __forceinline__

static constexpr int Bn = 64;     // batch
static constexpr int Tn = 512;    // time
static constexpr int En = 512;    // embed
static constexpr int Hn = 1024;   // hidden
static constexpr int Cn = 256;    // classes
static constexpr int Gn = 4 * Hn; // 4096 gates

typedef float v4f __attribute__((ext_vector_type(4)));
typedef unsigned int v4u __attribute__((ext_vector_type(4)));
typedef _Float16 v8h __attribute__((ext_vector_type(8)));

DEV_INLINE float sigmoidf_(float v) { return 1.f / (1.f + __expf(-v)); }

// ---------------------------------------------------------------------------
// fp32 tiled GEMM:  C[M,N] = A[M,K] * B[N,K]^T + bias1[n] (+bias2[n])
// (used for proj = embed @ W_ih^T + b_ih + b_hh)
// ---------------------------------------------------------------------------
__global__ __launch_bounds__(256) void gemm_tt(
    const float* __restrict__ A, const float* __restrict__ Bm,
    const float* __restrict__ bias1, const float* __restrict__ bias2,
    float* __restrict__ Cm, int M, int N, int K)
{
  constexpr int KC = 32;
  __shared__ float As[KC][68];
  __shared__ float Bs[KC][68];
  const int tid = threadIdx.x;
  const int tx = tid & 15, ty = tid >> 4;
  const int m0 = blockIdx.x * 64, n0 = blockIdx.y * 64;

  float acc[4][4] = {};

  for (int k0 = 0; k0 < K; k0 += KC) {
    __syncthreads();
    #pragma unroll
    for (int j = 0; j < 2; ++j) {
      int f = tid + j * 256;
      int row = f >> 3;
      int c4 = f & 7;
      float4 va = *reinterpret_cast<const float4*>(&A[(size_t)(m0 + row) * K + k0 + c4 * 4]);
      As[c4 * 4 + 0][row] = va.x; As[c4 * 4 + 1][row] = va.y;
      As[c4 * 4 + 2][row] = va.z; As[c4 * 4 + 3][row] = va.w;
      float4 vb = *reinterpret_cast<const float4*>(&Bm[(size_t)(n0 + row) * K + k0 + c4 * 4]);
      Bs[c4 * 4 + 0][row] = vb.x; Bs[c4 * 4 + 1][row] = vb.y;
      Bs[c4 * 4 + 2][row] = vb.z; Bs[c4 * 4 + 3][row] = vb.w;
    }
    __syncthreads();
    #pragma unroll
    for (int k = 0; k < KC; ++k) {
      float4 a4 = *reinterpret_cast<const float4*>(&As[k][ty * 4]);
      float4 b4 = *reinterpret_cast<const float4*>(&Bs[k][tx * 4]);
      float ar[4] = {a4.x, a4.y, a4.z, a4.w};
      float br[4] = {b4.x, b4.y, b4.z, b4.w};
      #pragma unroll
      for (int i = 0; i < 4; ++i)
        #pragma unroll
        for (int j = 0; j < 4; ++j)
          acc[i][j] += ar[i] * br[j];
    }
  }

  #pragma unroll
  for (int j = 0; j < 4; ++j) {
    int n = n0 + tx * 4 + j;
    float bb = bias1[n];
    if (bias2) bb += bias2[n];
    #pragma unroll
    for (int i = 0; i < 4; ++i)
      Cm[(size_t)(m0 + ty * 4 + i) * N + n] = acc[i][j] + bb;
  }
}

// ---------------------------------------------------------------------------
// FC GEMM reading fp16 A (hs16, layout [t][b][h], row index m = t*64+b),
// writing out[b][t][c] fp32.  out = A @ fc_W^T + fc_b.
// ---------------------------------------------------------------------------
__global__ __launch_bounds__(256) void gemm_fc(
    const _Float16* __restrict__ A,   // [32768][1024] fp16
    const float* __restrict__ Bm,     // fc_W [256][1024]
    const float* __restrict__ bias,   // fc_b [256]
    float* __restrict__ out)          // [64][512][256]
{
  constexpr int KC = 32;
  __shared__ float As[KC][68];
  __shared__ float Bs[KC][68];
  const int tid = threadIdx.x;
  const int tx = tid & 15, ty = tid >> 4;
  const int m0 = blockIdx.x * 64, n0 = blockIdx.y * 64;

  float acc[4][4] = {};

  for (int k0 = 0; k0 < Hn; k0 += KC) {
    __syncthreads();
    {
      int row = tid >> 2, c8 = tid & 3;     // 64 rows x 4 chunks of 8 halves
      v8h va = *(const v8h*)(A + (size_t)(m0 + row) * Hn + k0 + c8 * 8);
      #pragma unroll
      for (int e = 0; e < 8; ++e) As[c8 * 8 + e][row] = (float)va[e];
    }
    #pragma unroll
    for (int j = 0; j < 2; ++j) {
      int f = tid + j * 256, row = f >> 3, c4 = f & 7;
      float4 vb = *reinterpret_cast<const float4*>(&Bm[(size_t)(n0 + row) * Hn + k0 + c4 * 4]);
      Bs[c4 * 4 + 0][row] = vb.x; Bs[c4 * 4 + 1][row] = vb.y;
      Bs[c4 * 4 + 2][row] = vb.z; Bs[c4 * 4 + 3][row] = vb.w;
    }
    __syncthreads();
    #pragma unroll
    for (int k = 0; k < KC; ++k) {
      float4 a4 = *reinterpret_cast<const float4*>(&As[k][ty * 4]);
      float4 b4 = *reinterpret_cast<const float4*>(&Bs[k][tx * 4]);
      float ar[4] = {a4.x, a4.y, a4.z, a4.w};
      float br[4] = {b4.x, b4.y, b4.z, b4.w};
      #pragma unroll
      for (int i = 0; i < 4; ++i)
        #pragma unroll
        for (int j = 0; j < 4; ++j)
          acc[i][j] += ar[i] * br[j];
    }
  }

  #pragma unroll
  for (int j = 0; j < 4; ++j) {
    int n = n0 + tx * 4 + j;
    float bb = bias[n];
    #pragma unroll
    for (int i = 0; i < 4; ++i) {
      int m = m0 + ty * 4 + i;
      int b = m & 63, t = m >> 6;
      out[((size_t)b * Tn + t) * Cn + n] = acc[i][j] + bb;
    }
  }
}

// ---------------------------------------------------------------------------
// MFMA W-stationary persistent LSTM with tag-in-data exchange.
// 128 blocks x 512 threads. Block (bg=bid>>5, hg=bid&31): batches [bg*16,+16),
// h-cols [hg*32,+32). W fp16 fragments (32 x v8h) in regs, loaded once.
//
// Exchange: xbuf record = 16B {h0..h3 fp16, pad, tag16=0x4000+t in hi16 of
// dword3}, written by ONE global_store_dwordx4 sc0 sc1 (atomic 16B at the
// coherence point -> tag visible implies data visible; no producer drain,
// no separate flag). Ping-pong slots by t&1 (skew <= 1 step: a block stores
// t only after polling all t-1 tags => all t-2 reads complete). Consumers
// poll THEIR OWN data records: 8x16B = one 128B line per thread; on match
// the staging data is already in registers -> poll IS the staging.
// Replay-safe: exact tag match; xbuf memset each call; tags 0x4000..0x41FF
// unreachable by |h|<1 fp16 payloads.
// ---------------------------------------------------------------------------
__global__ __launch_bounds__(512, 2) void lstm_mfma(
    const int* __restrict__ x,        // [B, T]
    const float* __restrict__ Whh,    // [4H, H] fp32
    const float* __restrict__ proj,   // [C, 4H] incl. both biases
    _Float16* __restrict__ hs16,      // [T, B, H] fp16, FC input (plain stores)
    char* __restrict__ xbuf)          // [2][4][32][128] x 16B tagged records
{
  __shared__ __align__(16) char hT[32768];     // A-tile, fragment-linear
  __shared__ float gbuf[128 * 21];             // gate exchange, stride 21
  __shared__ _Float16 hstage[512];             // 16 x 32 fp16 h repack

  const int tid = threadIdx.x;
  const int bid = blockIdx.x;
  const int bg = bid >> 5, hg = bid & 31;
  const int b0 = bg * 16;

  const int w = tid >> 6, l = tid & 63;
  const int q = w >> 2, g = w & 3;
  const int mrow = l & 15;                     // B col in tile / A row
  const int kseg = l >> 4;                     // k-segment 0..3

  // ---- one-time W preload: fp32 -> fp16 fragments
  v8h wv[32];
  {
    const float* wr = Whh + (size_t)(g * Hn + hg * 32 + q * 16 + mrow) * Hn + kseg * 8;
    #pragma unroll
    for (int kk = 0; kk < 32; ++kk) {
      const float* p = wr + kk * 32;
      float4 f0 = *(const float4*)p, f1 = *(const float4*)(p + 4);
      v8h h8;
      h8[0] = (_Float16)f0.x; h8[1] = (_Float16)f0.y;
      h8[2] = (_Float16)f0.z; h8[3] = (_Float16)f0.w;
      h8[4] = (_Float16)f1.x; h8[5] = (_Float16)f1.y;
      h8[6] = (_Float16)f1.z; h8[7] = (_Float16)f1.w;
      wv[kk] = h8;
    }
  }

  // elementwise mapping: thread owns (batch eb, hcol ehc)
  const int eb = tid >> 5, ehc = tid & 31;
  const int* xp = x + (size_t)(b0 + eb) * Tn;
  float cst = 0.f;

  // consumer: thread reads producer kk=tid>>4, batch=tid&15, units i=0..7
  const int csrc = (tid >> 4) * 2048 + (tid & 15) * 128;
  const int dbase = (tid >> 4) * 1024 + (tid & 15) * 16;

  for (int t = 0; t < Tn; ++t) {
    const int cls = xp[t];
    // proj prefetch BEFORE the poll: L2 latency hides under the exchange wait
    const float* pb = proj + (size_t)cls * Gn + hg * 32 + ehc;
    float p0 = pb[0], p1 = pb[Hn], p2 = pb[2 * Hn], p3 = pb[3 * Hn];

    if (t > 0) {
      // ---- fused poll+stage: 8x16B (one 128B line) until all tags match
      const unsigned tagv = 0x4000u + (unsigned)(t - 1);
      const char* pp = xbuf + (size_t)((t - 1) & 1) * 262144 + bg * 65536 + csrc;
      v4u r0, r1, r2, r3, r4, r5, r6, r7;
      for (;;) {
        asm volatile(
          "global_load_dwordx4 %0, %8, off sc0 sc1\n\t"
          "global_load_dwordx4 %1, %8, off offset:16 sc0 sc1\n\t"
          "global_load_dwordx4 %2, %8, off offset:32 sc0 sc1\n\t"
          "global_load_dwordx4 %3, %8, off offset:48 sc0 sc1\n\t"
          "global_load_dwordx4 %4, %8, off offset:64 sc0 sc1\n\t"
          "global_load_dwordx4 %5, %8, off offset:80 sc0 sc1\n\t"
          "global_load_dwordx4 %6, %8, off offset:96 sc0 sc1\n\t"
          "global_load_dwordx4 %7, %8, off offset:112 sc0 sc1\n\t"
          "s_waitcnt vmcnt(0)"
          : "=&v"(r0), "=&v"(r1), "=&v"(r2), "=&v"(r3),
            "=&v"(r4), "=&v"(r5), "=&v"(r6), "=&v"(r7)
          : "v"(pp) : "memory");
        unsigned m = ((r0.w >> 16) ^ tagv) | ((r1.w >> 16) ^ tagv)
                   | ((r2.w >> 16) ^ tagv) | ((r3.w >> 16) ^ tagv)
                   | ((r4.w >> 16) ^ tagv) | ((r5.w >> 16) ^ tagv)
                   | ((r6.w >> 16) ^ tagv) | ((r7.w >> 16) ^ tagv);
        if (m == 0u) break;
      }
      // scatter payloads (8B each) into the fragment-linear A-tile
      v4u rr[8] = {r0, r1, r2, r3, r4, r5, r6, r7};
      #pragma unroll
      for (int i = 0; i < 8; ++i) {
        *(unsigned long long*)(hT + dbase + (i >> 1) * 256 + (i & 1) * 8)
          = ((unsigned long long)rr[i].y << 32) | (unsigned long long)rr[i].x;
      }
    }
    __syncthreads();

    v4f acc0 = {0.f, 0.f, 0.f, 0.f};
    v4f acc1 = {0.f, 0.f, 0.f, 0.f};
    if (t > 0) {
      #pragma unroll
      for (int kk = 0; kk < 32; kk += 2) {
        v8h a0 = *(const v8h*)(hT + kk * 1024 + l * 16);
        v8h a1 = *(const v8h*)(hT + (kk + 1) * 1024 + l * 16);
        acc0 = __builtin_amdgcn_mfma_f32_16x16x32_f16(a0, wv[kk], acc0, 0, 0, 0);
        acc1 = __builtin_amdgcn_mfma_f32_16x16x32_f16(a1, wv[kk + 1], acc1, 0, 0, 0);
      }
    }

    // D frag: col = l&15 (hc within q-half), row = 4*kseg + r (batch)
    #pragma unroll
    for (int r = 0; r < 4; ++r)
      gbuf[(g * 32 + q * 16 + mrow) * 21 + kseg * 4 + r] = acc0[r] + acc1[r];
    __syncthreads();

    // elementwise: all 512 threads, one (batch, hc) each
    {
      float g0 = gbuf[(0 * 32 + ehc) * 21 + eb] + p0;
      float g1 = gbuf[(1 * 32 + ehc) * 21 + eb] + p1;
      float g2 = gbuf[(2 * 32 + ehc) * 21 + eb] + p2;
      float g3 = gbuf[(3 * 32 + ehc) * 21 + eb] + p3;
      float ig = sigmoidf_(g0), fg = sigmoidf_(g1);
      float gg = tanhf(g2),     og = sigmoidf_(g3);
      cst = fg * cst + ig * gg;
      hstage[eb * 32 + ehc] = (_Float16)(og * tanhf(cst));
    }
    __syncthreads();

    // hs16 for the FC GEMM: plain cached stores (kernel-end flush suffices)
    if (tid < 64) {
      const int b = tid >> 2, part = tid & 3;
      *(v4f*)(hs16 + ((size_t)t * Bn + b0 + b) * Hn + hg * 32 + part * 8)
        = *(const v4f*)(hstage + b * 32 + part * 8);
    }
    // publish tagged exchange records: fire-and-forget single 16B stores
    if (tid < 128) {
      const int batch = tid >> 3, cg = tid & 7;
      unsigned long long d =
          *(const unsigned long long*)(hstage + batch * 32 + cg * 4);
      v4u val;
      val.x = (unsigned)d;
      val.y = (unsigned)(d >> 32);
      val.z = 0u;
      val.w = (0x4000u + (unsigned)t) << 16;
      char* dst = xbuf + (size_t)(t & 1) * 262144 + bg * 65536
                + hg * 2048 + tid * 16;
      asm volatile("global_store_dwordx4 %0, %1, off sc0 sc1"
                   :: "v"(dst), "v"(val) : "memory");
    }
    // next iteration's poll (vmcnt 0) orders everything else.
  }
}

// ---------------------------------------------------------------------------
extern "C" void kernel_launch(void* const* d_in, const int* in_sizes, int n_in,
                              void* d_out, int out_size, void* d_ws, size_t ws_size,
                              hipStream_t stream) {
  const int*   x     = (const int*)  d_in[0];
  const float* embed = (const float*)d_in[1];
  const float* Wih   = (const float*)d_in[2];
  const float* Whh   = (const float*)d_in[3];
  const float* bih   = (const float*)d_in[4];
  const float* bhh   = (const float*)d_in[5];
  const float* fcW   = (const float*)d_in[6];
  const float* fcb   = (const float*)d_in[7];
  float* out = (float*)d_out;

  char* ws = (char*)d_ws;
  const size_t xbufBytes = 524288;                                     // 512 KB
  const size_t projBytes = (size_t)Cn * Gn * sizeof(float);            // 4 MB
  const size_t hsBytes   = (size_t)Tn * Bn * Hn * sizeof(_Float16);    // 64 MB
  const size_t need = xbufBytes + projBytes + hsBytes;
  if (ws_size < need) {
    hipMemsetAsync(d_out, 0, (size_t)out_size * sizeof(float), stream);
    return;
  }
  float*     proj = (float*)(ws + xbufBytes);
  _Float16*  hs16 = (_Float16*)(ws + xbufBytes + projBytes);

  // clear exchange records every call: no stale/garbage tag can match
  hipMemsetAsync(d_ws, 0, xbufBytes, stream);

  // 1) proj[cls, 4H] = embed[cls,:] @ W_ih^T + b_ih + b_hh
  dim3 g1(Cn / 64, Gn / 64);   // (4, 64)
  gemm_tt<<<g1, 256, 0, stream>>>(embed, Wih, bih, bhh, proj, Cn, Gn, En);

  // 2) MFMA W-stationary persistent recurrence (tag-in-data exchange)
  lstm_mfma<<<128, 512, 0, stream>>>(x, Whh, proj, hs16, ws);

  // 3) out[b,t,:] = hs16[t,b,:] @ fc_W^T + fc_b
  dim3 g3((Bn * Tn) / 64, Cn / 64);  // (512, 4)
  gemm_fc<<<g3, 256, 0, stream>>>(hs16, fcW, fcb, out);
}